// Round 4
// baseline (63.444 us; speedup 1.0000x reference)
//
#include <hip/hip_runtime.h>
#include <hip/hip_bf16.h>
#include <hip/hip_cooperative_groups.h>

// Shapes (fixed by the reference)
constexpr int IN_F  = 1024;
constexpr int OUT_F = 1024;
constexpr int LAT   = 16;
constexpr int BATCH = 256;

typedef __attribute__((ext_vector_type(8))) short  bf16x8;  // 8 bf16 (4 VGPRs)
typedef __attribute__((ext_vector_type(4))) float  f32x4;   // MFMA accumulator

static __device__ __forceinline__ unsigned short bf16_bits(float v) {
  __hip_bfloat16 h = __float2bfloat16(v);
  return *reinterpret_cast<unsigned short*>(&h);
}

// ---------------------------------------------------------------------------
// Single cooperative kernel.
// Phase 1 (block b): s = z[b] @ lt_w^T + lt_b; xs[b]=bf16(x*s); ss[b]=bf16(s^2)
// grid.sync()
// Phase 2 (block b): output tile n0=(b&31)*32, m0=(b>>5)*32:
//   acc1 = xs @ W, acc2 = ss @ W^2  (W transposed+converted in-kernel)
//   out = acc1 * rsqrt(acc2 + 1e-8) + bias
// 256 blocks (1/CU, co-resident), 256 threads (4 waves, 2x2 of 16x16 MFMA).
// ---------------------------------------------------------------------------
__global__ __launch_bounds__(256) void fused_mod(
    const float* __restrict__ tensor, const float* __restrict__ z,
    const float* __restrict__ lt_w, const float* __restrict__ lt_b,
    const float* __restrict__ W, const float* __restrict__ bias,
    __hip_bfloat16* xs, __hip_bfloat16* ss, float* __restrict__ out) {
  __shared__ __hip_bfloat16 lds[2][4][32 * 64];  // [buf][xs,ss,wt,w2t] 32KB

  const int bid = blockIdx.x;
  const int t = threadIdx.x;

  // ---------------- Phase 1: prep batch row b = bid ----------------
  {
    const int b = bid;
    float zr[LAT];
    const float4* z4 = reinterpret_cast<const float4*>(z + b * LAT);
#pragma unroll
    for (int j = 0; j < LAT / 4; ++j) {
      float4 v = z4[j];
      zr[4 * j + 0] = v.x; zr[4 * j + 1] = v.y;
      zr[4 * j + 2] = v.z; zr[4 * j + 3] = v.w;
    }
    const int i0 = t * 4;  // 256 threads x 4 elements = 1024
    float s[4];
#pragma unroll
    for (int j = 0; j < 4; ++j) {
      const float4* lw = reinterpret_cast<const float4*>(lt_w + (i0 + j) * LAT);
      float acc = lt_b[i0 + j];
#pragma unroll
      for (int q = 0; q < LAT / 4; ++q) {
        float4 v = lw[q];
        acc += zr[4 * q + 0] * v.x + zr[4 * q + 1] * v.y +
               zr[4 * q + 2] * v.z + zr[4 * q + 3] * v.w;
      }
      s[j] = acc;
    }
    const float4 x = *reinterpret_cast<const float4*>(tensor + b * IN_F + i0);
    union { unsigned short u[4]; uint2 v; } pxs, pss;
    pxs.u[0] = bf16_bits(x.x * s[0]); pss.u[0] = bf16_bits(s[0] * s[0]);
    pxs.u[1] = bf16_bits(x.y * s[1]); pss.u[1] = bf16_bits(s[1] * s[1]);
    pxs.u[2] = bf16_bits(x.z * s[2]); pss.u[2] = bf16_bits(s[2] * s[2]);
    pxs.u[3] = bf16_bits(x.w * s[3]); pss.u[3] = bf16_bits(s[3] * s[3]);
    *reinterpret_cast<uint2*>(xs + b * IN_F + i0) = pxs.v;
    *reinterpret_cast<uint2*>(ss + b * IN_F + i0) = pss.v;
  }

  // grid-wide barrier: all xs/ss rows visible device-wide after this
  cooperative_groups::this_grid().sync();

  // ---------------- Phase 2: fused double-GEMM + demod ----------------
  const int n0 = (bid & 31) * 32;   // same-n0 blocks differ by 32 -> same XCD
  const int m0 = (bid >> 5) * 32;
  const int lane = t & 63;
  const int wave = t >> 6;
  const int wm = wave >> 1;
  const int wn = wave & 1;

  // A staging map: thread t -> (row = t>>3, 16B chunk c = t&7)
  const int srow = t >> 3;
  const int sc = t & 7;
  const int swz_off = srow * 128 + ((sc ^ (srow & 7)) << 4);
  const int gofs_a = (m0 + srow) * IN_F + sc * 8;

  // W staging map: thread t -> column n_l = t&31, k-octet kr = t>>5
  const int wn_l = t & 31;
  const int wkr = t >> 5;  // 0..7
  const int wswz = wn_l * 128 + ((wkr ^ (wn_l & 7)) << 4);
  const int wg_base = (wkr * 8) * OUT_F + n0 + wn_l;  // add k0*OUT_F per iter

  // fragment addressing (proven layout)
  const int frow = lane & 15;
  const int h = lane >> 4;
  const int arow = wm * 16 + frow;
  const int brow = wn * 16 + frow;
  const int aoff0 = arow * 128 + (((0 + h) ^ (arow & 7)) << 4);
  const int aoff1 = arow * 128 + (((4 + h) ^ (arow & 7)) << 4);
  const int boff0 = brow * 128 + (((0 + h) ^ (brow & 7)) << 4);
  const int boff1 = brow * 128 + (((4 + h) ^ (brow & 7)) << 4);

  f32x4 acc1 = {0.f, 0.f, 0.f, 0.f};
  f32x4 acc2 = {0.f, 0.f, 0.f, 0.f};

  // prologue: K-tile 0 loads
  bf16x8 ra = *reinterpret_cast<const bf16x8*>(xs + gofs_a);
  bf16x8 rb = *reinterpret_cast<const bf16x8*>(ss + gofs_a);
  float wv[8];
#pragma unroll
  for (int j = 0; j < 8; ++j) wv[j] = W[wg_base + j * OUT_F];

#pragma unroll
  for (int tstep = 0; tstep < IN_F / 64; ++tstep) {
    char* l0 = reinterpret_cast<char*>(lds[tstep & 1][0]);
    char* l1 = reinterpret_cast<char*>(lds[tstep & 1][1]);
    char* l2 = reinterpret_cast<char*>(lds[tstep & 1][2]);
    char* l3 = reinterpret_cast<char*>(lds[tstep & 1][3]);
    // convert current W regs (bf16 + squared bf16), then stage everything
    union { unsigned short u[8]; bf16x8 v; } pw, pw2;
#pragma unroll
    for (int j = 0; j < 8; ++j) {
      pw.u[j]  = bf16_bits(wv[j]);
      pw2.u[j] = bf16_bits(wv[j] * wv[j]);
    }
    *reinterpret_cast<bf16x8*>(l0 + swz_off) = ra;
    *reinterpret_cast<bf16x8*>(l1 + swz_off) = rb;
    *reinterpret_cast<bf16x8*>(l2 + wswz) = pw.v;
    *reinterpret_cast<bf16x8*>(l3 + wswz) = pw2.v;
    __syncthreads();
    // issue next tile's global loads (hidden under ds_read + MFMA below)
    if (tstep < IN_F / 64 - 1) {
      const int k0 = (tstep + 1) * 64;
      ra = *reinterpret_cast<const bf16x8*>(xs + gofs_a + k0);
      rb = *reinterpret_cast<const bf16x8*>(ss + gofs_a + k0);
#pragma unroll
      for (int j = 0; j < 8; ++j) wv[j] = W[k0 * OUT_F + wg_base + j * OUT_F];
    }
    // MFMA on current buffer (two K=32 sub-steps)
    bf16x8 a1 = *reinterpret_cast<const bf16x8*>(l0 + aoff0);
    bf16x8 a2 = *reinterpret_cast<const bf16x8*>(l1 + aoff0);
    bf16x8 b1 = *reinterpret_cast<const bf16x8*>(l2 + boff0);
    bf16x8 b2 = *reinterpret_cast<const bf16x8*>(l3 + boff0);
    acc1 = __builtin_amdgcn_mfma_f32_16x16x32_bf16(a1, b1, acc1, 0, 0, 0);
    acc2 = __builtin_amdgcn_mfma_f32_16x16x32_bf16(a2, b2, acc2, 0, 0, 0);
    a1 = *reinterpret_cast<const bf16x8*>(l0 + aoff1);
    a2 = *reinterpret_cast<const bf16x8*>(l1 + aoff1);
    b1 = *reinterpret_cast<const bf16x8*>(l2 + boff1);
    b2 = *reinterpret_cast<const bf16x8*>(l3 + boff1);
    acc1 = __builtin_amdgcn_mfma_f32_16x16x32_bf16(a1, b1, acc1, 0, 0, 0);
    acc2 = __builtin_amdgcn_mfma_f32_16x16x32_bf16(a2, b2, acc2, 0, 0, 0);
  }

  // epilogue: C/D layout is col = lane&15, row = (lane>>4)*4 + reg
  const int col = n0 + wn * 16 + (lane & 15);
  const float bs = bias[col];
#pragma unroll
  for (int q = 0; q < 4; ++q) {
    const int row = m0 + wm * 16 + (lane >> 4) * 4 + q;
    out[row * OUT_F + col] = acc1[q] * __frsqrt_rn(acc2[q] + 1e-8f) + bs;
  }
}

// ---------------------------------------------------------------------------
extern "C" void kernel_launch(void* const* d_in, const int* in_sizes, int n_in,
                              void* d_out, int out_size, void* d_ws, size_t ws_size,
                              hipStream_t stream) {
  const float* tensor = (const float*)d_in[0];  // [256][1024]
  const float* z      = (const float*)d_in[1];  // [256][16]
  const float* W      = (const float*)d_in[2];  // [1024][1024]
  const float* bias   = (const float*)d_in[3];  // [1024]
  const float* lt_w   = (const float*)d_in[4];  // [1024][16]
  const float* lt_b   = (const float*)d_in[5];  // [1024]
  float* out = (float*)d_out;

  // workspace: xs[512K] ss[512K] bf16
  char* ws = (char*)d_ws;
  __hip_bfloat16* xsb = (__hip_bfloat16*)(ws);
  __hip_bfloat16* ssb = (__hip_bfloat16*)(ws + 512 * 1024);

  void* args[] = {(void*)&tensor, (void*)&z, (void*)&lt_w, (void*)&lt_b,
                  (void*)&W, (void*)&bias, (void*)&xsb, (void*)&ssb,
                  (void*)&out};
  hipLaunchCooperativeKernel((const void*)fused_mod, dim3(256), dim3(256),
                             args, 0, stream);
}

// Round 5
// 18.863 us; speedup vs baseline: 3.3635x; 3.3635x over previous
//
#include <hip/hip_runtime.h>
#include <hip/hip_bf16.h>

// Shapes (fixed by the reference)
constexpr int IN_F  = 1024;
constexpr int OUT_F = 1024;
constexpr int LAT   = 16;
constexpr int BATCH = 256;

typedef __attribute__((ext_vector_type(8))) short  bf16x8;  // 8 bf16 (4 VGPRs)
typedef __attribute__((ext_vector_type(4))) float  f32x4;   // MFMA accumulator

static __device__ __forceinline__ unsigned short bf16_bits(float v) {
  __hip_bfloat16 h = __float2bfloat16(v);
  return *reinterpret_cast<unsigned short*>(&h);
}
static __device__ __forceinline__ float bf16_f32(unsigned short u) {
  __hip_bfloat16 h;
  *reinterpret_cast<unsigned short*>(&h) = u;
  return __bfloat162float(h);
}

// ---------------------------------------------------------------------------
// Single kernel, NO grid sync. Block bid -> tile n0=(bid&31)*32, m0=(bid>>5)*32.
// Phase A: s[32][1024] for this block's 32 batch rows via MFMA:
//   s = z @ lt_w^T + lt_b, K=16 padded into K=32 slots as [hi|lo] split:
//   MFMA1: A=[z_hi|z_lo] x B=[w_hi|w_hi]; MFMA2: A x B=[w_lo|0]  => ~f32 exact.
//   Stored bf16 in LDS, XOR-swizzled [row][k-chunk] (chunk=16B, c ^= row&7).
// Phase B (proven R2/R3 structure): double-buffered K-loop; A-staging computes
//   xs=bf16(x*s), ss=bf16(s*s) from global x (f32) and LDS s; W staged with
//   in-register transpose+square. acc1=xs@W, acc2=ss@W^2;
//   out = acc1*rsqrt(acc2+1e-8)+bias.
// 256 blocks (1/CU), 256 threads (4 waves, 2x2 of 16x16 MFMA tiles). LDS 96KB.
// ---------------------------------------------------------------------------
__global__ __launch_bounds__(256) void fused_mod(
    const float* __restrict__ tensor, const float* __restrict__ z,
    const float* __restrict__ lt_w, const float* __restrict__ lt_b,
    const float* __restrict__ W, const float* __restrict__ bias,
    float* __restrict__ out) {
  __shared__ __hip_bfloat16 s_lds[32 * 1024];        // 64KB: s for 32 m-rows
  __shared__ __hip_bfloat16 tiles[2][4][32 * 64];    // 32KB: dbuf xs,ss,wt,w2t

  const int bid = blockIdx.x;
  const int t = threadIdx.x;
  const int n0 = (bid & 31) * 32;   // same-n0 blocks: bid mod 8 equal -> same XCD
  const int m0 = (bid >> 5) * 32;
  const int lane = t & 63;
  const int wave = t >> 6;

  // ---- staging maps (phase B), computed early ----
  const int srow = t >> 3;          // 0..31
  const int sc = t & 7;             // 0..7
  const int swz_off = srow * 128 + ((sc ^ (srow & 7)) << 4);  // tile byte off
  const int xg = (m0 + srow) * IN_F + sc * 8;                 // f32 index
  const int wn_l = t & 31;
  const int wkr = t >> 5;
  const int wswz = wn_l * 128 + ((wkr ^ (wn_l & 7)) << 4);
  const int wg_base = (wkr * 8) * OUT_F + n0 + wn_l;

  // ---- prologue global loads for K-iter 0 (hide under phase A) ----
  float4 xa = *reinterpret_cast<const float4*>(tensor + xg);
  float4 xb = *reinterpret_cast<const float4*>(tensor + xg + 4);
  float wv[8];
#pragma unroll
  for (int j = 0; j < 8; ++j) wv[j] = W[wg_base + j * OUT_F];

  // ================= Phase A: s via MFMA =================
  {
    const int lm = lane & 15;   // A row / B col / D col
    const int h = lane >> 4;    // 0..3
    const int koct = h & 1;     // which 8 of the 16 K values
    // A-frags (z rows), [hi|lo] split across h<2 / h>=2
    bf16x8 afrag[2];
#pragma unroll
    for (int mt = 0; mt < 2; ++mt) {
      const float* zp = z + (m0 + mt * 16 + lm) * LAT + koct * 8;
      float4 v0 = *reinterpret_cast<const float4*>(zp);
      float4 v1 = *reinterpret_cast<const float4*>(zp + 4);
      float v[8] = {v0.x, v0.y, v0.z, v0.w, v1.x, v1.y, v1.z, v1.w};
      union { unsigned short u[8]; bf16x8 b; } fa;
#pragma unroll
      for (int j = 0; j < 8; ++j) {
        unsigned short hi = bf16_bits(v[j]);
        fa.u[j] = (h < 2) ? hi : bf16_bits(v[j] - bf16_f32(hi));
      }
      afrag[mt] = fa.b;
    }
    // 16 i-tiles per wave (64 total): i = it*16 + lm
    for (int itl = 0; itl < 16; ++itl) {
      const int it = wave * 16 + itl;
      const int i = it * 16 + lm;
      const float* wp = lt_w + i * LAT + koct * 8;
      float4 v0 = *reinterpret_cast<const float4*>(wp);
      float4 v1 = *reinterpret_cast<const float4*>(wp + 4);
      float v[8] = {v0.x, v0.y, v0.z, v0.w, v1.x, v1.y, v1.z, v1.w};
      union { unsigned short u[8]; bf16x8 b; } f1, f2;
#pragma unroll
      for (int j = 0; j < 8; ++j) {
        unsigned short hi = bf16_bits(v[j]);
        f1.u[j] = hi;                                           // w_hi (both halves)
        f2.u[j] = (h < 2) ? bf16_bits(v[j] - bf16_f32(hi)) : 0; // [w_lo|0]
      }
      const float bsum = lt_b[i];
      const int c = i >> 3;  // 16B chunk index in s_lds row
#pragma unroll
      for (int mt = 0; mt < 2; ++mt) {
        f32x4 sacc = {0.f, 0.f, 0.f, 0.f};
        sacc = __builtin_amdgcn_mfma_f32_16x16x32_bf16(afrag[mt], f1.b, sacc, 0, 0, 0);
        sacc = __builtin_amdgcn_mfma_f32_16x16x32_bf16(afrag[mt], f2.b, sacc, 0, 0, 0);
#pragma unroll
        for (int q = 0; q < 4; ++q) {
          const int r = mt * 16 + h * 4 + q;  // D row = (lane>>4)*4+q
          const int off = r * 2048 + ((c ^ (r & 7)) << 4) + (lm & 7) * 2;
          *reinterpret_cast<unsigned short*>(
              reinterpret_cast<char*>(s_lds) + off) = bf16_bits(sacc[q] + bsum);
        }
      }
    }
  }
  __syncthreads();  // s_lds ready (read-only from here on)

  // ================= Phase B: double-GEMM K-loop =================
  const int frow = lane & 15;
  const int h = lane >> 4;
  const int wm = wave >> 1;
  const int wn = wave & 1;
  const int arow = wm * 16 + frow;
  const int brow = wn * 16 + frow;
  const int aoff0 = arow * 128 + (((0 + h) ^ (arow & 7)) << 4);
  const int aoff1 = arow * 128 + (((4 + h) ^ (arow & 7)) << 4);
  const int boff0 = brow * 128 + (((0 + h) ^ (brow & 7)) << 4);
  const int boff1 = brow * 128 + (((4 + h) ^ (brow & 7)) << 4);

  f32x4 acc1 = {0.f, 0.f, 0.f, 0.f};
  f32x4 acc2 = {0.f, 0.f, 0.f, 0.f};

  // first s fragment (chunk c = sc for tstep 0)
  bf16x8 s8 = *reinterpret_cast<const bf16x8*>(
      reinterpret_cast<char*>(s_lds) + srow * 2048 + ((sc ^ (srow & 7)) << 4));

#pragma unroll
  for (int tstep = 0; tstep < IN_F / 64; ++tstep) {
    char* l0 = reinterpret_cast<char*>(tiles[tstep & 1][0]);
    char* l1 = reinterpret_cast<char*>(tiles[tstep & 1][1]);
    char* l2 = reinterpret_cast<char*>(tiles[tstep & 1][2]);
    char* l3 = reinterpret_cast<char*>(tiles[tstep & 1][3]);
    // build xs/ss from x (regs) and s (LDS frag), W tiles from wv regs
    union { unsigned short u[8]; bf16x8 b; } pxs, pss, pw, pw2;
    const float xv[8] = {xa.x, xa.y, xa.z, xa.w, xb.x, xb.y, xb.z, xb.w};
#pragma unroll
    for (int j = 0; j < 8; ++j) {
      const float sf = bf16_f32((unsigned short)s8[j]);
      pxs.u[j] = bf16_bits(xv[j] * sf);
      pss.u[j] = bf16_bits(sf * sf);
      pw.u[j]  = bf16_bits(wv[j]);
      pw2.u[j] = bf16_bits(wv[j] * wv[j]);
    }
    *reinterpret_cast<bf16x8*>(l0 + swz_off) = pxs.b;
    *reinterpret_cast<bf16x8*>(l1 + swz_off) = pss.b;
    *reinterpret_cast<bf16x8*>(l2 + wswz) = pw.b;
    *reinterpret_cast<bf16x8*>(l3 + wswz) = pw2.b;
    __syncthreads();
    // prefetch next K-tile inputs (hidden under ds_read + MFMA below)
    if (tstep < IN_F / 64 - 1) {
      const int k0 = (tstep + 1) * 64;
      xa = *reinterpret_cast<const float4*>(tensor + xg + k0);
      xb = *reinterpret_cast<const float4*>(tensor + xg + k0 + 4);
      const int cs = (tstep + 1) * 8 + sc;
      s8 = *reinterpret_cast<const bf16x8*>(
          reinterpret_cast<char*>(s_lds) + srow * 2048 + ((cs ^ (srow & 7)) << 4));
#pragma unroll
      for (int j = 0; j < 8; ++j) wv[j] = W[k0 * OUT_F + wg_base + j * OUT_F];
    }
    // MFMA on current buffer (two K=32 sub-steps) — proven section
    bf16x8 a1 = *reinterpret_cast<const bf16x8*>(l0 + aoff0);
    bf16x8 a2 = *reinterpret_cast<const bf16x8*>(l1 + aoff0);
    bf16x8 b1 = *reinterpret_cast<const bf16x8*>(l2 + boff0);
    bf16x8 b2 = *reinterpret_cast<const bf16x8*>(l3 + boff0);
    acc1 = __builtin_amdgcn_mfma_f32_16x16x32_bf16(a1, b1, acc1, 0, 0, 0);
    acc2 = __builtin_amdgcn_mfma_f32_16x16x32_bf16(a2, b2, acc2, 0, 0, 0);
    a1 = *reinterpret_cast<const bf16x8*>(l0 + aoff1);
    a2 = *reinterpret_cast<const bf16x8*>(l1 + aoff1);
    b1 = *reinterpret_cast<const bf16x8*>(l2 + boff1);
    b2 = *reinterpret_cast<const bf16x8*>(l3 + boff1);
    acc1 = __builtin_amdgcn_mfma_f32_16x16x32_bf16(a1, b1, acc1, 0, 0, 0);
    acc2 = __builtin_amdgcn_mfma_f32_16x16x32_bf16(a2, b2, acc2, 0, 0, 0);
  }

  // epilogue: C/D layout col = lane&15, row = (lane>>4)*4 + reg
  const int col = n0 + wn * 16 + (lane & 15);
  const float bs = bias[col];
#pragma unroll
  for (int q = 0; q < 4; ++q) {
    const int row = m0 + wm * 16 + (lane >> 4) * 4 + q;
    out[row * OUT_F + col] = acc1[q] * __frsqrt_rn(acc2[q] + 1e-8f) + bs;
  }
}

// ---------------------------------------------------------------------------
extern "C" void kernel_launch(void* const* d_in, const int* in_sizes, int n_in,
                              void* d_out, int out_size, void* d_ws, size_t ws_size,
                              hipStream_t stream) {
  const float* tensor = (const float*)d_in[0];  // [256][1024]
  const float* z      = (const float*)d_in[1];  // [256][16]
  const float* W      = (const float*)d_in[2];  // [1024][1024]
  const float* bias   = (const float*)d_in[3];  // [1024]
  const float* lt_w   = (const float*)d_in[4];  // [1024][16]
  const float* lt_b   = (const float*)d_in[5];  // [1024]
  float* out = (float*)d_out;

  fused_mod<<<256, 256, 0, stream>>>(tensor, z, lt_w, lt_b, W, bias, out);
}